// Round 3
// baseline (1606.852 us; speedup 1.0000x reference)
//
#include <hip/hip_runtime.h>

#define Bdim 64
#define Ndim 512
#define Hdim 2048
#define KSPLIT 8
#define OCH 64
#define NCHUNK 8
#define LNEPS 1e-5f

typedef unsigned short u16;

__device__ __forceinline__ u16 f2bf(float f) {
    unsigned int u = __float_as_uint(f);
    return (u16)((u + 0x7FFFu + ((u >> 16) & 1u)) >> 16);
}
__device__ __forceinline__ float bf2f(u16 s) {
    return __uint_as_float(((unsigned int)s) << 16);
}

__global__ void init_k(int* cnt) {
    if (threadIdx.x < 64) cnt[threadIdx.x] = 0;
}

// Fused GEMV: Y[b,o] = sum_k X[b,k]*Weff[o,k] (+bias) (+Y_old)
// WMODE 0: Weff[o,k] = W[o*H+k]  (Y = X @ W^T)
// WMODE 1: Weff[o,k] = W[k*H+o]  (Y = X @ W)
// Grid: 256 blocks = 8 k-splits x 32 o-chunks(64). Last block per o-chunk
// combines partials in fixed ks order (deterministic), adds bias/residual.
template<int WMODE, int HASBIAS, int ACC, int DOFIN, int FINAL>
__global__ __launch_bounds__(256)
void gemv_f(const float* __restrict__ X, const float* __restrict__ W,
            const float* __restrict__ bias, float* __restrict__ part,
            int* __restrict__ cnt, float* __restrict__ Y,
            float* __restrict__ out, int has_loss)
{
    __shared__ float Xs[64][68];     // pad 68: read is 4-addr broadcast, 2-way max
    __shared__ float Ws[64][64];     // XOR col-quad swizzle: quad q of row o at q^((o>>2)&7)
    __shared__ int flagS;
    const int t  = threadIdx.x;
    const int oc = blockIdx.x & 31;
    const int ks = blockIdx.x >> 5;
    const int o0 = oc * OCH;
    const int k0 = ks * 256;
    const int bg = t >> 4;      // 0..15
    const int og = t & 15;      // 0..15

    float4 xr[4], wr[4];
    auto loadc = [&](int kb) {
#pragma unroll
        for (int i = 0; i < 4; ++i) {
            const int r = i * 16 + bg;
            xr[i] = *(const float4*)(X + (size_t)r * Hdim + kb + og * 4);
            if (WMODE == 0)
                wr[i] = *(const float4*)(W + (size_t)(o0 + r) * Hdim + kb + og * 4);
            else
                wr[i] = *(const float4*)(W + (size_t)(kb + r) * Hdim + o0 + og * 4);
        }
    };
    auto storec = [&]() {
#pragma unroll
        for (int i = 0; i < 4; ++i) {
            const int r = i * 16 + bg;
            *(float4*)(&Xs[r][og * 4]) = xr[i];
            if (WMODE == 0) {
                *(float4*)(&Ws[r][(og ^ ((r >> 2) & 7)) << 2]) = wr[i];
            } else {
                // wr[i] holds W[kb+r][o0+og*4 .. +3] -> scatter-transpose
                const int col = ((((r >> 2) ^ (og & 7)) << 2) | (r & 3));
                Ws[og * 4 + 0][col] = wr[i].x;
                Ws[og * 4 + 1][col] = wr[i].y;
                Ws[og * 4 + 2][col] = wr[i].z;
                Ws[og * 4 + 3][col] = wr[i].w;
            }
        }
    };

    float acc[4][4];
#pragma unroll
    for (int j = 0; j < 4; ++j)
#pragma unroll
        for (int oi = 0; oi < 4; ++oi) acc[j][oi] = 0.f;

    loadc(k0);
#pragma unroll
    for (int c = 0; c < 4; ++c) {
        __syncthreads();
        storec();
        __syncthreads();
        if (c < 3) loadc(k0 + (c + 1) * 64);   // prefetch overlaps compute
#pragma unroll
        for (int kkq = 0; kkq < 16; ++kkq) {
            float4 xj[4];
#pragma unroll
            for (int j = 0; j < 4; ++j)
                xj[j] = *(const float4*)(&Xs[bg * 4 + j][kkq * 4]);
#pragma unroll
            for (int oi = 0; oi < 4; ++oi) {
                float4 w = *(const float4*)(&Ws[og * 4 + oi][(kkq ^ (og & 7)) << 2]);
#pragma unroll
                for (int j = 0; j < 4; ++j) {
                    acc[j][oi] += xj[j].x * w.x + xj[j].y * w.y
                                + xj[j].z * w.z + xj[j].w * w.w;
                }
            }
        }
    }
#pragma unroll
    for (int j = 0; j < 4; ++j) {
        const int b = bg * 4 + j;
        float4 v = make_float4(acc[j][0], acc[j][1], acc[j][2], acc[j][3]);
        *(float4*)(part + (size_t)(ks * 64 + b) * Hdim + o0 + og * 4) = v;
    }
    if (DOFIN) {
        __threadfence();
        __syncthreads();
        if (t == 0) {
            int old = atomicAdd(cnt + oc, 1);
            flagS = (old == KSPLIT - 1) ? 1 : 0;
        }
        __syncthreads();
        if (flagS) {
            __threadfence();
#pragma unroll
            for (int i = 0; i < 4; ++i) {
                const int flat = i * 256 + t;   // 0..1023 = 64 b x 16 o-quads
                const int b  = flat >> 4;
                const int o  = o0 + (flat & 15) * 4;
                float4 v;
                if (HASBIAS) v = *(const float4*)(bias + o);
                else         v = make_float4(0.f, 0.f, 0.f, 0.f);
#pragma unroll
                for (int s = 0; s < KSPLIT; ++s) {
                    float4 p = *(const float4*)(part + (size_t)(s * 64 + b) * Hdim + o);
                    v.x += p.x; v.y += p.y; v.z += p.z; v.w += p.w;
                }
                if (ACC) {
                    float4 a = *(const float4*)(Y + (size_t)b * Hdim + o);
                    v.x += a.x; v.y += a.y; v.z += a.z; v.w += a.w;
                }
                *(float4*)(Y + (size_t)b * Hdim + o) = v;
                if (FINAL) *(float4*)(out + (size_t)b * Hdim + o) = v;
            }
            if (t == 0) {
                if (FINAL && has_loss && oc == 0) out[Bdim * Hdim] = 0.f;
                cnt[oc] = 0;    // self-reset for next gemv (stream-ordered)
            }
        }
    }
}

// One (b, 8-row n-chunk): theta_l from partials, scores -> local softmax ->
// partial weighted lfb sum (bf16 out).
__global__ __launch_bounds__(256)
void flash_chunk(const float* __restrict__ lfb, const float* __restrict__ thpart,
                 float scale, u16* __restrict__ up,
                 float* __restrict__ wm, float* __restrict__ wz)
{
    __shared__ u16 T[NCHUNK][Hdim];   // 32 KB
    __shared__ float th[Hdim];        // 8 KB
    __shared__ float sc[NCHUNK];
    __shared__ float wts[NCHUNK];
    const int t  = threadIdx.x;
    const int b  = blockIdx.x >> 6;
    const int ch = blockIdx.x & 63;
    const float* src = lfb + ((size_t)b * Ndim + ch * NCHUNK) * Hdim;
#pragma unroll
    for (int i = 0; i < 16; ++i) {
        int flat4 = i * 256 + t;
        int row   = flat4 >> 9;
        int c4    = flat4 & 511;
        float4 v  = *(const float4*)(src + (size_t)row * Hdim + c4 * 4);
        ushort4 u4;
        u4.x = f2bf(v.x); u4.y = f2bf(v.y); u4.z = f2bf(v.z); u4.w = f2bf(v.w);
        *(ushort4*)(&T[row][c4 * 4]) = u4;
    }
#pragma unroll
    for (int i = 0; i < 2; ++i) {
        int c = (i * 256 + t) * 4;
        float4 v = make_float4(0.f, 0.f, 0.f, 0.f);
#pragma unroll
        for (int s = 0; s < KSPLIT; ++s) {
            float4 p = *(const float4*)(thpart + (size_t)(s * 64 + b) * Hdim + c);
            v.x += p.x; v.y += p.y; v.z += p.z; v.w += p.w;
        }
        *(float4*)(&th[c]) = v;
    }
    __syncthreads();
    const int wv = t >> 6, ln = t & 63;
#pragma unroll
    for (int q = 0; q < 2; ++q) {
        int n = wv * 2 + q;
        float a = 0.f;
#pragma unroll
        for (int i = 0; i < 8; ++i) {
            int c = ln * 4 + i * 256;
            ushort4 x = *(const ushort4*)(&T[n][c]);
            float4 y  = *(const float4*)(&th[c]);
            a += bf2f(x.x) * y.x + bf2f(x.y) * y.y + bf2f(x.z) * y.z + bf2f(x.w) * y.w;
        }
#pragma unroll
        for (int off = 32; off; off >>= 1) a += __shfl_xor(a, off, 64);
        if (ln == 0) sc[n] = a * scale;
    }
    __syncthreads();
    float m = sc[0];
#pragma unroll
    for (int n = 1; n < NCHUNK; ++n) m = fmaxf(m, sc[n]);
    if (t < NCHUNK) wts[t] = expf(sc[t] - m);
    __syncthreads();
    if (t == 0) {
        float z = 0.f;
#pragma unroll
        for (int n = 0; n < NCHUNK; ++n) z += wts[n];
        wm[blockIdx.x] = m;
        wz[blockIdx.x] = z;
    }
#pragma unroll
    for (int i = 0; i < 8; ++i) {
        int c = t + i * 256;
        float a = 0.f;
#pragma unroll
        for (int n = 0; n < NCHUNK; ++n) a += wts[n] * bf2f(T[n][c]);
        up[(size_t)blockIdx.x * Hdim + c] = f2bf(a);
    }
}

__global__ __launch_bounds__(256)
void flash_comb(const u16* __restrict__ up, const float* __restrict__ wm,
                const float* __restrict__ wz, float* __restrict__ u)
{
    __shared__ float mm[64], zz[64], ee[64];
    const int t  = threadIdx.x;
    const int b  = blockIdx.x >> 3;
    const int sl = blockIdx.x & 7;
    if (t < 64) { mm[t] = wm[b * 64 + t]; zz[t] = wz[b * 64 + t]; }
    __syncthreads();
    float mg = mm[0];
#pragma unroll
    for (int i = 1; i < 64; ++i) mg = fmaxf(mg, mm[i]);
    if (t < 64) ee[t] = expf(mm[t] - mg);
    __syncthreads();
    float Z = 0.f;
#pragma unroll
    for (int i = 0; i < 64; ++i) Z += zz[i] * ee[i];
    const float inv = 1.f / Z;
    const int col = sl * 256 + t;
    float a = 0.f;
#pragma unroll 8
    for (int ch = 0; ch < 64; ++ch)
        a += ee[ch] * bf2f(up[(size_t)(b * 64 + ch) * Hdim + col]);
    u[(size_t)b * Hdim + col] = a * inv;
}

// r = relu(layernorm(t)), t already has its bias
__global__ __launch_bounds__(256)
void ln_relu(const float* __restrict__ tin, float* __restrict__ r)
{
    __shared__ float red[8];
    const int t = threadIdx.x, b = blockIdx.x;
    float4 v0, v1;
    float sum = 0.f, sq = 0.f;
    {
        int c0 = t * 4, c1 = (256 + t) * 4;
        v0 = *(const float4*)(tin + (size_t)b * Hdim + c0);
        v1 = *(const float4*)(tin + (size_t)b * Hdim + c1);
        sum = v0.x + v0.y + v0.z + v0.w + v1.x + v1.y + v1.z + v1.w;
        sq  = v0.x*v0.x + v0.y*v0.y + v0.z*v0.z + v0.w*v0.w
            + v1.x*v1.x + v1.y*v1.y + v1.z*v1.z + v1.w*v1.w;
    }
#pragma unroll
    for (int off = 32; off; off >>= 1) {
        sum += __shfl_xor(sum, off, 64);
        sq  += __shfl_xor(sq,  off, 64);
    }
    if ((t & 63) == 0) { red[t >> 6] = sum; red[4 + (t >> 6)] = sq; }
    __syncthreads();
    sum = red[0] + red[1] + red[2] + red[3];
    sq  = red[4] + red[5] + red[6] + red[7];
    const float mu   = sum * (1.f / Hdim);
    const float var  = sq * (1.f / Hdim) - mu * mu;
    const float rstd = rsqrtf(var + LNEPS);
    float4 o0, o1;
    o0.x = fmaxf(0.f, (v0.x - mu) * rstd); o0.y = fmaxf(0.f, (v0.y - mu) * rstd);
    o0.z = fmaxf(0.f, (v0.z - mu) * rstd); o0.w = fmaxf(0.f, (v0.w - mu) * rstd);
    o1.x = fmaxf(0.f, (v1.x - mu) * rstd); o1.y = fmaxf(0.f, (v1.y - mu) * rstd);
    o1.z = fmaxf(0.f, (v1.z - mu) * rstd); o1.w = fmaxf(0.f, (v1.w - mu) * rstd);
    *(float4*)(r + (size_t)b * Hdim + t * 4)         = o0;
    *(float4*)(r + (size_t)b * Hdim + (256 + t) * 4) = o1;
}

extern "C" void kernel_launch(void* const* d_in, const int* in_sizes, int n_in,
                              void* d_out, int out_size, void* d_ws, size_t ws_size,
                              hipStream_t stream) {
    (void)in_sizes; (void)n_in; (void)ws_size;
    const float* clip = (const float*)d_in[0];
    const float* lfb  = (const float*)d_in[1];
    const float* Wc   = (const float*)d_in[2];
    const float* bc   = (const float*)d_in[3];
    const float* Wl   = (const float*)d_in[4];
    const float* bl   = (const float*)d_in[5];
    const float* Wt   = (const float*)d_in[6];
    const float* bt   = (const float*)d_in[7];
    const float* Wp   = (const float*)d_in[8];
    // d_in[9] = bp: cancels in softmax (per-row constant) -> unused
    const float* Wg   = (const float*)d_in[10];
    const float* bg   = (const float*)d_in[11];
    const float* Wo   = (const float*)d_in[12];
    const float* bo   = (const float*)d_in[13];
    float* out = (float*)d_out;

    // Workspace layout (float offsets). NOTE: up is 4096*2048 u16 =
    // 4,194,304 FLOAT slots (16 MB) — wm/wz/cnt must start AFTER that.
    float* wsf = (float*)d_ws;
    float* A    = wsf;                    // 131072
    float* v1   = wsf + 131072;
    float* v2   = wsf + 262144;
    float* u    = wsf + 393216;
    float* part = wsf + 524288;           // 8*64*2048 = 1048576 -> ends 1572864
    u16*   up   = (u16*)(wsf + 1572864);  // 8,388,608 u16 = 4,194,304 f32 slots
    float* wm   = wsf + 1572864 + 4194304;    // 4096
    float* wz   = wm + 4096;                  // 4096
    int*   cnt  = (int*)(wz + 4096);          // 64 ints
    // total ~5.78M floats = 23.1 MB

    const float scale = 0.022097086912079608f;   // 1/sqrt(2048)
    dim3 blk(256);
    const int has_loss = (out_size > Bdim * Hdim) ? 1 : 0;

    init_k<<<1, 64, 0, stream>>>(cnt);

    // A = clip @ Wc^T + bc
    gemv_f<0,1,0,1,0><<<256, blk, 0, stream>>>(clip, Wc, bc, part, cnt, A, nullptr, 0);

    for (int l = 0; l < 3; ++l) {
        // theta = A @ Wt^T + bt
        gemv_f<0,1,0,1,0><<<256, blk, 0, stream>>>(A, Wt, bt, part, cnt, v1, nullptr, 0);
        // thetap = theta @ Wp
        gemv_f<1,0,0,1,0><<<256, blk, 0, stream>>>(v1, Wp, nullptr, part, cnt, v2, nullptr, 0);
        // thetal partials = thetap @ Wl (no finisher; flash sums partials)
        gemv_f<1,0,0,0,0><<<256, blk, 0, stream>>>(v2, Wl, nullptr, part, cnt, nullptr, nullptr, 0);
        // fused scores/softmax/weighted-sum
        flash_chunk<<<4096, blk, 0, stream>>>(lfb, part, scale, up, wm, wz);
        flash_comb<<<512, blk, 0, stream>>>(up, wm, wz, u);
        // s = u @ Wl^T + bl
        gemv_f<0,1,0,1,0><<<256, blk, 0, stream>>>(u, Wl, bl, part, cnt, v1, nullptr, 0);
        // t = s @ Wg^T + bg
        gemv_f<0,1,0,1,0><<<256, blk, 0, stream>>>(v1, Wg, bg, part, cnt, v2, nullptr, 0);
        // r = relu(LN(t))
        ln_relu<<<64, blk, 0, stream>>>(v2, v1);
        // A += r @ Wo^T + bo   (last layer also writes out + loss)
        if (l < 2)
            gemv_f<0,1,1,1,0><<<256, blk, 0, stream>>>(v1, Wo, bo, part, cnt, A, nullptr, 0);
        else
            gemv_f<0,1,1,1,1><<<256, blk, 0, stream>>>(v1, Wo, bo, part, cnt, A, out, has_loss);
    }
}